// Round 1
// baseline (267.143 us; speedup 1.0000x reference)
//
#include <hip/hip_runtime.h>
#include <math.h>

#define BATCH 4
#define NN    12288
#define CIN   3
#define NC    4096            // nodes per (batch, channel) group
#define NG    12              // BATCH * CIN groups
#define NSL   4               // sender slices (one per wave)
#define SLICE (NC / NSL)      // 1024 senders per wave

// workspace layout (floats)
#define A_OFF 16                          // scaled spikes a = 0.25*s/rng, [NG*NC]
#define S_OFF (A_OFF + NG * NC)           // sin(theta), float4 per node
#define C_OFF (S_OFF + NG * NC * 4)      // cos(theta), float4 per node
// total floats = C_OFF + NG*NC*4 = 442384  (~1.77 MB)

// ---------------- kernel 1: per-group range -> scale = 0.25/max(rng,1e-6) ----
__global__ void k_rng(const float* __restrict__ spikes, float* __restrict__ ws) {
    int g = blockIdx.x;                 // 0..11
    int b = g / CIN, c = g % CIN;
    const float* sp = spikes + b * NN;
    float mn = 1e30f, mx = -1e30f;
    for (int k = threadIdx.x; k < NC; k += 256) {
        float s = sp[k * CIN + c];
        mn = fminf(mn, s);
        mx = fmaxf(mx, s);
    }
    #pragma unroll
    for (int off = 32; off > 0; off >>= 1) {
        mn = fminf(mn, __shfl_down(mn, off));
        mx = fmaxf(mx, __shfl_down(mx, off));
    }
    __shared__ float smn[4], smx[4];
    int w = threadIdx.x >> 6;
    if ((threadIdx.x & 63) == 0) { smn[w] = mn; smx[w] = mx; }
    __syncthreads();
    if (threadIdx.x == 0) {
        mn = fminf(fminf(smn[0], smn[1]), fminf(smn[2], smn[3]));
        mx = fmaxf(fmaxf(smx[0], smx[1]), fmaxf(smx[2], smx[3]));
        float rng = fmaxf(mx - mn, 1e-6f);
        ws[g] = 0.25f / rng;
    }
}

// ---------------- kernel 2: pack a, sin(theta), cos(theta) ------------------
__global__ void k_pack(const float* __restrict__ theta,
                       const float* __restrict__ spikes,
                       float* __restrict__ ws) {
    int u = blockIdx.x * 256 + threadIdx.x;   // 0..NG*NC-1
    int g = u >> 12;                          // NC = 4096
    int k = u & (NC - 1);
    int b = g / CIN, c = g % CIN;
    int v = b * NN + k * CIN + c;             // flat node index in [B*N)
    float scale = ws[g];
    float a = spikes[v] * scale;
    float4 th = ((const float4*)theta)[v];
    float4 s4, c4;
    sincosf(th.x, &s4.x, &c4.x);
    sincosf(th.y, &s4.y, &c4.y);
    sincosf(th.z, &s4.z, &c4.z);
    sincosf(th.w, &s4.w, &c4.w);
    ws[A_OFF + u] = a;
    ((float4*)(ws + S_OFF))[u] = s4;
    ((float4*)(ws + C_OFF))[u] = c4;
}

// ---------------- kernel 3: all-pairs coupling + epilogue -------------------
// grid: NG * (NC/64) = 768 blocks, 256 threads.
// block -> group g, receiver tile of 64; wave w sums senders [w*1024,(w+1)*1024)
__launch_bounds__(256, 3)
__global__ void k_couple(const float* __restrict__ gamma,
                         float* __restrict__ out,
                         const float* __restrict__ ws) {
    int g     = blockIdx.x >> 6;
    int rtile = blockIdx.x & 63;
    int lane  = threadIdx.x & 63;
    int w     = threadIdx.x >> 6;
    int gbase = g << 12;
    int kr    = rtile * 64 + lane;            // receiver within group

    const float*  A  = ws + A_OFF;
    const float4* S  = (const float4*)(ws + S_OFF);
    const float4* Cc = (const float4*)(ws + C_OFF);

    float ai = A[gbase + kr];
    float4 U = make_float4(0.f, 0.f, 0.f, 0.f);
    float4 V = make_float4(0.f, 0.f, 0.f, 0.f);

    int j = gbase + w * SLICE;
    #pragma unroll 4
    for (int jj = 0; jj < SLICE; ++jj, ++j) {
        float  aj = A[j];
        float4 sj = S[j];
        float4 cj = Cc[j];
        float ds = ai - aj;
        float t  = fabsf(ds);
        float t2 = ds * ds;
        // cos(t) ~ 1 - t^2/2 + t^4/24 ; sin(t) ~ t - t^3/6   (t in [0,0.25])
        float cosA = fmaf(t2, fmaf(t2, (1.f / 24.f), -0.5f), 1.f);
        float sinA = t * fmaf(t2, (-1.f / 6.f), 1.f);
        float aff  = 0.25f - t;
        float P = aff * cosA;
        float Q = aff * sinA;
        U.x = fmaf(P, sj.x, U.x); U.x = fmaf(-Q, cj.x, U.x);
        U.y = fmaf(P, sj.y, U.y); U.y = fmaf(-Q, cj.y, U.y);
        U.z = fmaf(P, sj.z, U.z); U.z = fmaf(-Q, cj.z, U.z);
        U.w = fmaf(P, sj.w, U.w); U.w = fmaf(-Q, cj.w, U.w);
        V.x = fmaf(P, cj.x, V.x); V.x = fmaf(Q, sj.x, V.x);
        V.y = fmaf(P, cj.y, V.y); V.y = fmaf(Q, sj.y, V.y);
        V.z = fmaf(P, cj.z, V.z); V.z = fmaf(Q, sj.z, V.z);
        V.w = fmaf(P, cj.w, V.w); V.w = fmaf(Q, sj.w, V.w);
    }

    __shared__ float red[NSL][64][9];   // pad 9 to avoid bank conflicts
    float* pr = &red[w][lane][0];
    pr[0] = U.x; pr[1] = U.y; pr[2] = U.z; pr[3] = U.w;
    pr[4] = V.x; pr[5] = V.y; pr[6] = V.z; pr[7] = V.w;
    __syncthreads();

    if (threadIdx.x < 64) {
        int r = threadIdx.x;
        float acc[8];
        #pragma unroll
        for (int i = 0; i < 8; ++i)
            acc[i] = (red[0][r][i] + red[1][r][i]) + (red[2][r][i] + red[3][r][i]);

        int kr2 = rtile * 64 + r;
        float4 si = S[gbase + kr2];
        float4 ci = Cc[gbase + kr2];
        int b = g / CIN, c = g % CIN;
        int v = b * NN + kr2 * CIN + c;
        float4 g4 = ((const float4*)gamma)[v];

        const float kInv = 1.0f / (float)NC;   // COUPLING / n
        float tx = fmaf(kInv, ci.x * acc[0] - si.x * acc[4], g4.x);
        float ty = fmaf(kInv, ci.y * acc[1] - si.y * acc[5], g4.y);
        float tz = fmaf(kInv, ci.z * acc[2] - si.z * acc[6], g4.z);
        float tw = fmaf(kInv, ci.w * acc[3] - si.w * acc[7], g4.w);

        float nrm = sqrtf(tx * tx + ty * ty + tz * tz + tw * tw);
        float inv = 1.0f / fmaxf(nrm, 1e-6f);
        ((float4*)out)[v] = make_float4(tx * inv, ty * inv, tz * inv, tw * inv);
    }
}

extern "C" void kernel_launch(void* const* d_in, const int* in_sizes, int n_in,
                              void* d_out, int out_size, void* d_ws, size_t ws_size,
                              hipStream_t stream) {
    const float* theta  = (const float*)d_in[0];
    const float* gamma  = (const float*)d_in[1];
    const float* spikes = (const float*)d_in[2];
    float* out = (float*)d_out;
    float* ws  = (float*)d_ws;

    hipLaunchKernelGGL(k_rng,    dim3(NG),          dim3(256), 0, stream, spikes, ws);
    hipLaunchKernelGGL(k_pack,   dim3(NG * NC/256), dim3(256), 0, stream, theta, spikes, ws);
    hipLaunchKernelGGL(k_couple, dim3(NG * 64),     dim3(256), 0, stream, gamma, out, ws);
}

// Round 2
// 91.772 us; speedup vs baseline: 2.9109x; 2.9109x over previous
//
#include <hip/hip_runtime.h>
#include <math.h>

#define BATCH 4
#define NN    12288
#define CIN   3
#define NC    4096
#define NG    12

// workspace layout (float offsets)
#define A_OFF    0                       // a_all [NG*NC]
#define RANK_OFF (A_OFF + NG*NC)         // int [NG*NC]
#define CP_OFF   (RANK_OFF + NG*NC)      // coupling [BATCH*NN*4]
// total = 49152 + 49152 + 196608 floats = 1.18 MB

typedef unsigned long long u64;

// ---------- kernel 1: per-group range, a = 0.25*s/rng, zero ranks ----------
__launch_bounds__(1024)
__global__ void k_prep(const float* __restrict__ spikes, float* __restrict__ ws) {
    int g = blockIdx.x, b = g / CIN, c = g % CIN;
    int tid = threadIdx.x, lane = tid & 63, w = tid >> 6;
    float s[4]; float mn = 1e30f, mx = -1e30f;
    #pragma unroll
    for (int q = 0; q < 4; ++q) {
        int k = tid + q * 1024;
        s[q] = spikes[b * NN + k * CIN + c];
        mn = fminf(mn, s[q]); mx = fmaxf(mx, s[q]);
    }
    #pragma unroll
    for (int off = 32; off > 0; off >>= 1) {
        mn = fminf(mn, __shfl_down(mn, off));
        mx = fmaxf(mx, __shfl_down(mx, off));
    }
    __shared__ float smn[16], smx[16], sscale;
    if (lane == 0) { smn[w] = mn; smx[w] = mx; }
    __syncthreads();
    if (tid == 0) {
        float m0 = smn[0], m1 = smx[0];
        for (int i = 1; i < 16; ++i) { m0 = fminf(m0, smn[i]); m1 = fmaxf(m1, smx[i]); }
        sscale = 0.25f / fmaxf(m1 - m0, 1e-6f);
    }
    __syncthreads();
    float scale = sscale;
    int* rank = (int*)(ws + RANK_OFF);
    #pragma unroll
    for (int q = 0; q < 4; ++q) {
        int k = tid + q * 1024;
        ws[A_OFF + g * NC + k] = s[q] * scale;
        rank[g * NC + k] = 0;
    }
}

// ---------- kernel 2: rank = #{unique keys < mine} (j-split + atomicAdd) ----
__global__ void k_count(float* __restrict__ ws) {
    __shared__ u64 sKey[1024];
    int bid = blockIdx.x;
    int g = bid >> 6, it = (bid >> 2) & 15, jt = bid & 3;
    const float* A = ws + A_OFF + g * NC;
    int tid = threadIdx.x;
    int i = it * 256 + tid;
    float ai = A[i];
    u64 ki = ((u64)__float_as_uint(ai) << 12) | (unsigned)i;

    int jbase = jt * 1024;
    float4 f4 = ((const float4*)(A + jbase))[tid];
    int j0 = jbase + tid * 4;
    sKey[tid * 4 + 0] = ((u64)__float_as_uint(f4.x) << 12) | (unsigned)(j0 + 0);
    sKey[tid * 4 + 1] = ((u64)__float_as_uint(f4.y) << 12) | (unsigned)(j0 + 1);
    sKey[tid * 4 + 2] = ((u64)__float_as_uint(f4.z) << 12) | (unsigned)(j0 + 2);
    sKey[tid * 4 + 3] = ((u64)__float_as_uint(f4.w) << 12) | (unsigned)(j0 + 3);
    __syncthreads();

    int cnt = 0;
    const ulonglong2* K2 = (const ulonglong2*)sKey;
    #pragma unroll 8
    for (int q = 0; q < 512; ++q) {
        ulonglong2 kk = K2[q];
        cnt += (kk.x < ki);
        cnt += (kk.y < ki);
    }
    atomicAdd(&((int*)(ws + RANK_OFF))[g * NC + i], cnt);
}

// ---------- kernel 3: per (group,dim): sorted scans -> coupling ------------
__launch_bounds__(1024)
__global__ void k_scan(const float* __restrict__ theta, float* __restrict__ ws) {
    __shared__ float sA[NC];
    __shared__ int   sIdx[NC];
    __shared__ float wsum[16][9];
    __shared__ float wexcl[16][9];
    __shared__ float wtot[8];

    int bid = blockIdx.x, g = bid >> 2, d = bid & 3;
    int b = g / CIN, c = g % CIN;
    int tid = threadIdx.x, lane = tid & 63, w = tid >> 6;

    const float* A = ws + A_OFF + g * NC;
    const int*   R = (const int*)(ws + RANK_OFF) + g * NC;

    // scatter to sorted order in LDS
    #pragma unroll
    for (int q = 0; q < 4; ++q) {
        int k = tid + q * 1024;
        int r = R[k];
        sA[r] = A[k];
        sIdx[r] = k;
    }
    __syncthreads();

    float vals[4][8]; float aq[4]; int vq[4];
    #pragma unroll
    for (int q = 0; q < 4; ++q) {
        int r = tid * 4 + q;
        float a = sA[r]; int k = sIdx[r];
        int v = b * NN + k * CIN + c;
        vq[q] = v; aq[q] = a;
        float th = theta[v * 4 + d];
        float sth, cth, sa, ca;
        sincosf(th, &sth, &cth);
        sincosf(a, &sa, &ca);
        float sf = fmaf(cth, sa,  sth * ca);   // sin(th+a)
        float cf = fmaf(-sth, sa, cth * ca);   // cos(th+a)
        float sp = fmaf(-cth, sa, sth * ca);   // sin(th-a)
        float cp = fmaf(sth, sa,  cth * ca);   // cos(th-a)
        vals[q][0] = sf;     vals[q][1] = cf;
        vals[q][2] = a * sf; vals[q][3] = a * cf;
        vals[q][4] = sp;     vals[q][5] = cp;
        vals[q][6] = a * sp; vals[q][7] = a * cp;
    }

    float own[8], incl[8];
    #pragma unroll
    for (int ch = 0; ch < 8; ++ch) {
        own[ch] = ((vals[0][ch] + vals[1][ch]) + (vals[2][ch] + vals[3][ch]));
        incl[ch] = own[ch];
    }
    // wave64 inclusive scan of thread totals
    #pragma unroll
    for (int off = 1; off < 64; off <<= 1) {
        #pragma unroll
        for (int ch = 0; ch < 8; ++ch) {
            float o = __shfl_up(incl[ch], off);
            if (lane >= off) incl[ch] += o;
        }
    }
    if (lane == 63) {
        #pragma unroll
        for (int ch = 0; ch < 8; ++ch) wsum[w][ch] = incl[ch];
    }
    __syncthreads();
    if (w == 0 && lane < 16) {
        float x[8], in2[8];
        #pragma unroll
        for (int ch = 0; ch < 8; ++ch) { x[ch] = wsum[lane][ch]; in2[ch] = x[ch]; }
        #pragma unroll
        for (int off = 1; off < 16; off <<= 1) {
            #pragma unroll
            for (int ch = 0; ch < 8; ++ch) {
                float o = __shfl_up(in2[ch], off);
                if (lane >= off) in2[ch] += o;
            }
        }
        #pragma unroll
        for (int ch = 0; ch < 8; ++ch) wexcl[lane][ch] = in2[ch] - x[ch];
        if (lane == 15) {
            #pragma unroll
            for (int ch = 0; ch < 8; ++ch) wtot[ch] = in2[ch];
        }
    }
    __syncthreads();

    float ebt[8], tot[8], run[8];
    #pragma unroll
    for (int ch = 0; ch < 8; ++ch) {
        ebt[ch] = wexcl[w][ch] + incl[ch] - own[ch];   // exclusive before this thread
        tot[ch] = wtot[ch];
        run[ch] = 0.f;
    }

    float* CP = ws + CP_OFF;
    #pragma unroll
    for (int q = 0; q < 4; ++q) {
        float P[8];
        #pragma unroll
        for (int ch = 0; ch < 8; ++ch) { run[ch] += vals[q][ch]; P[ch] = ebt[ch] + run[ch]; }
        float a = aq[q];
        float lowS = fmaf(0.25f - a, P[0], P[2]);
        float lowC = fmaf(0.25f - a, P[1], P[3]);
        float lower = vals[q][1] * lowS - vals[q][0] * lowC;
        float S4 = tot[4] - P[4], S5 = tot[5] - P[5];
        float S6 = tot[6] - P[6], S7 = tot[7] - P[7];
        float upS = fmaf(0.25f + a, S4, -S6);
        float upC = fmaf(0.25f + a, S5, -S7);
        float upper = vals[q][5] * upS - vals[q][4] * upC;
        CP[vq[q] * 4 + d] = (lower + upper) * (1.0f / (float)NC);
    }
}

// ---------- kernel 4: theta_next = gamma + coupling, normalize -------------
__global__ void k_norm(const float* __restrict__ gamma,
                       const float* __restrict__ ws,
                       float* __restrict__ out) {
    int u = blockIdx.x * 256 + threadIdx.x;   // < BATCH*NN
    float4 cp = ((const float4*)(ws + CP_OFF))[u];
    float4 g4 = ((const float4*)gamma)[u];
    float tx = g4.x + cp.x, ty = g4.y + cp.y, tz = g4.z + cp.z, tw = g4.w + cp.w;
    float nrm = sqrtf(tx * tx + ty * ty + tz * tz + tw * tw);
    float inv = 1.0f / fmaxf(nrm, 1e-6f);
    ((float4*)out)[u] = make_float4(tx * inv, ty * inv, tz * inv, tw * inv);
}

extern "C" void kernel_launch(void* const* d_in, const int* in_sizes, int n_in,
                              void* d_out, int out_size, void* d_ws, size_t ws_size,
                              hipStream_t stream) {
    const float* theta  = (const float*)d_in[0];
    const float* gamma  = (const float*)d_in[1];
    const float* spikes = (const float*)d_in[2];
    float* out = (float*)d_out;
    float* ws  = (float*)d_ws;

    hipLaunchKernelGGL(k_prep,  dim3(NG),            dim3(1024), 0, stream, spikes, ws);
    hipLaunchKernelGGL(k_count, dim3(NG * 64),       dim3(256),  0, stream, ws);
    hipLaunchKernelGGL(k_scan,  dim3(NG * 4),        dim3(1024), 0, stream, theta, ws);
    hipLaunchKernelGGL(k_norm,  dim3(BATCH*NN/256),  dim3(256),  0, stream, gamma, ws, out);
}

// Round 3
// 83.657 us; speedup vs baseline: 3.1933x; 1.0970x over previous
//
#include <hip/hip_runtime.h>
#include <math.h>

#define BATCH 4
#define NN    12288
#define CIN   3
#define NC    4096
#define NG    12

// workspace layout (float-element offsets)
#define ASORT 0                        // sorted a            [NG*NC]
#define ISORT (NG*NC)                  // sorted natural idx  [NG*NC] (int)
#define VALS  (2*NG*NC)                // per (g,d,r): 8 ch   [NG*4*NC*8]
#define CPOFF (VALS + NG*4*NC*8)       // coupling            [BATCH*NN*4]

// ---------- kernel 1: min/max -> a, counting sort by (a, idx) --------------
__launch_bounds__(1024)
__global__ void k_sort(const float* __restrict__ spikes, float* __restrict__ ws) {
    __shared__ float sA[NC];
    __shared__ int   sIdx[NC];
    __shared__ int   hist[NC];      // histogram, then exclusive bucket starts
    __shared__ int   cursor[NC];
    __shared__ float redmn[16], redmx[16];
    __shared__ float uAmin, uInv, uScale;
    __shared__ int   wsumI[16], wexclI[16];

    int g = blockIdx.x, b = g / CIN, c = g % CIN;
    int tid = threadIdx.x, lane = tid & 63, w = tid >> 6;

    float s[4];
    #pragma unroll
    for (int q = 0; q < 4; ++q) s[q] = spikes[b*NN + (tid + q*1024)*CIN + c];
    float mn = fminf(fminf(s[0], s[1]), fminf(s[2], s[3]));
    float mx = fmaxf(fmaxf(s[0], s[1]), fmaxf(s[2], s[3]));
    #pragma unroll
    for (int off = 32; off; off >>= 1) {
        mn = fminf(mn, __shfl_down(mn, off));
        mx = fmaxf(mx, __shfl_down(mx, off));
    }
    if (lane == 0) { redmn[w] = mn; redmx[w] = mx; }
    #pragma unroll
    for (int q = 0; q < 4; ++q) hist[tid + q*1024] = 0;
    __syncthreads();
    if (tid == 0) {
        float m0 = redmn[0], m1 = redmx[0];
        for (int i = 1; i < 16; ++i) { m0 = fminf(m0, redmn[i]); m1 = fmaxf(m1, redmx[i]); }
        float scale = 0.25f / fmaxf(m1 - m0, 1e-6f);
        uScale = scale;
        uAmin  = m0 * scale;
        uInv   = (float)NC / fmaxf((m1 - m0) * scale, 1e-30f);
    }
    __syncthreads();
    float scale = uScale, amin = uAmin, inv = uInv;

    float a[4]; int bk[4];
    #pragma unroll
    for (int q = 0; q < 4; ++q) {
        a[q] = s[q] * scale;
        int bb = (int)((a[q] - amin) * inv);
        bb = bb < 0 ? 0 : (bb > NC - 1 ? NC - 1 : bb);
        bk[q] = bb;
        atomicAdd(&hist[bb], 1);
    }
    __syncthreads();

    // exclusive scan of hist[4096] (each thread owns buckets tid*4..tid*4+3)
    int h0 = hist[tid*4+0], h1 = hist[tid*4+1], h2 = hist[tid*4+2], h3 = hist[tid*4+3];
    int i0 = h0, i1 = i0 + h1, i2 = i1 + h2, i3 = i2 + h3;
    int incl = i3;
    #pragma unroll
    for (int off = 1; off < 64; off <<= 1) {
        int o = __shfl_up(incl, off);
        if (lane >= off) incl += o;
    }
    if (lane == 63) wsumI[w] = incl;
    __syncthreads();
    if (w == 0 && lane < 16) {
        int x = wsumI[lane], v = x;
        #pragma unroll
        for (int off = 1; off < 16; off <<= 1) {
            int o = __shfl_up(v, off);
            if (lane >= off) v += o;
        }
        wexclI[lane] = v - x;
    }
    __syncthreads();
    int ebt = wexclI[w] + incl - i3;
    hist[tid*4+0] = ebt;        cursor[tid*4+0] = ebt;
    hist[tid*4+1] = ebt + i0;   cursor[tid*4+1] = ebt + i0;
    hist[tid*4+2] = ebt + i1;   cursor[tid*4+2] = ebt + i1;
    hist[tid*4+3] = ebt + i2;   cursor[tid*4+3] = ebt + i2;
    __syncthreads();

    // scatter (arrival order within bucket is nondeterministic; fixed below)
    #pragma unroll
    for (int q = 0; q < 4; ++q) {
        int slot = atomicAdd(&cursor[bk[q]], 1);
        sA[slot] = a[q];
        sIdx[slot] = tid + q*1024;
    }
    __syncthreads();

    // per-bucket insertion sort by (a, idx) -> deterministic total order
    #pragma unroll
    for (int q = 0; q < 4; ++q) {
        int bb = tid*4 + q;
        int lo = hist[bb];
        int hi = (bb == NC - 1) ? NC : hist[bb + 1];
        for (int x = lo + 1; x < hi; ++x) {
            float av = sA[x]; int iv = sIdx[x];
            int y = x - 1;
            while (y >= lo && (sA[y] > av || (sA[y] == av && sIdx[y] > iv))) {
                sA[y+1] = sA[y]; sIdx[y+1] = sIdx[y]; --y;
            }
            sA[y+1] = av; sIdx[y+1] = iv;
        }
    }
    __syncthreads();

    int* isort = (int*)ws + ISORT;
    #pragma unroll
    for (int q = 0; q < 4; ++q) {
        int r = tid + q*1024;
        ws[ASORT + g*NC + r] = sA[r];
        isort[g*NC + r] = sIdx[r];
    }
}

// ---------- kernel 2: trig per sorted element, all 4 dims ------------------
__global__ void k_vals(const float* __restrict__ theta, float* __restrict__ ws) {
    int u = blockIdx.x * 256 + threadIdx.x;      // < NG*NC
    int g = u >> 12, b = g / CIN, c = g % CIN;
    int r = u & (NC - 1);
    float a = ws[ASORT + u];
    int k = ((const int*)ws)[ISORT + u];
    int v = b*NN + k*CIN + c;
    float4 th = ((const float4*)theta)[v];
    float sa, ca; sincosf(a, &sa, &ca);
    float thv[4] = {th.x, th.y, th.z, th.w};
    #pragma unroll
    for (int d = 0; d < 4; ++d) {
        float sth, cth; sincosf(thv[d], &sth, &cth);
        float sf = fmaf(cth, sa,  sth * ca);     // sin(th + a)
        float cf = fmaf(-sth, sa, cth * ca);     // cos(th + a)
        float sp = fmaf(-cth, sa, sth * ca);     // sin(th - a)
        float cp = fmaf(sth, sa,  cth * ca);     // cos(th - a)
        float4* dst = (float4*)(ws + VALS + (size_t)(((g*4 + d) << 12) | r) * 8);
        dst[0] = make_float4(sf, cf, a * sf, a * cf);
        dst[1] = make_float4(sp, cp, a * sp, a * cp);
    }
}

// ---------- kernel 3: per (group,dim) 8-channel scan -> coupling -----------
__launch_bounds__(1024)
__global__ void k_scan(float* __restrict__ ws) {
    __shared__ float wsum[16][9];
    __shared__ float wexcl[16][9];
    __shared__ float wtot[8];

    int bid = blockIdx.x, g = bid >> 2, d = bid & 3;
    int b = g / CIN, c = g % CIN;
    int tid = threadIdx.x, lane = tid & 63, w = tid >> 6;

    const float4* V = (const float4*)(ws + VALS + (size_t)((g*4 + d) << 12) * 8);
    float vals[4][8];
    #pragma unroll
    for (int q = 0; q < 4; ++q) {
        float4 v0 = V[(tid*4 + q)*2];
        float4 v1 = V[(tid*4 + q)*2 + 1];
        vals[q][0] = v0.x; vals[q][1] = v0.y; vals[q][2] = v0.z; vals[q][3] = v0.w;
        vals[q][4] = v1.x; vals[q][5] = v1.y; vals[q][6] = v1.z; vals[q][7] = v1.w;
    }
    float4 aq4 = ((const float4*)(ws + ASORT + g*NC))[tid];
    int4   kq4 = ((const int4*)((const int*)ws + ISORT + g*NC))[tid];
    float aq[4] = {aq4.x, aq4.y, aq4.z, aq4.w};
    int vq[4] = {b*NN + kq4.x*CIN + c, b*NN + kq4.y*CIN + c,
                 b*NN + kq4.z*CIN + c, b*NN + kq4.w*CIN + c};

    float own[8], incl[8];
    #pragma unroll
    for (int ch = 0; ch < 8; ++ch) {
        own[ch] = (vals[0][ch] + vals[1][ch]) + (vals[2][ch] + vals[3][ch]);
        incl[ch] = own[ch];
    }
    #pragma unroll
    for (int off = 1; off < 64; off <<= 1) {
        #pragma unroll
        for (int ch = 0; ch < 8; ++ch) {
            float o = __shfl_up(incl[ch], off);
            if (lane >= off) incl[ch] += o;
        }
    }
    if (lane == 63) {
        #pragma unroll
        for (int ch = 0; ch < 8; ++ch) wsum[w][ch] = incl[ch];
    }
    __syncthreads();
    if (w == 0 && lane < 16) {
        float x[8], in2[8];
        #pragma unroll
        for (int ch = 0; ch < 8; ++ch) { x[ch] = wsum[lane][ch]; in2[ch] = x[ch]; }
        #pragma unroll
        for (int off = 1; off < 16; off <<= 1) {
            #pragma unroll
            for (int ch = 0; ch < 8; ++ch) {
                float o = __shfl_up(in2[ch], off);
                if (lane >= off) in2[ch] += o;
            }
        }
        #pragma unroll
        for (int ch = 0; ch < 8; ++ch) wexcl[lane][ch] = in2[ch] - x[ch];
        if (lane == 15) {
            #pragma unroll
            for (int ch = 0; ch < 8; ++ch) wtot[ch] = in2[ch];
        }
    }
    __syncthreads();

    float ebt[8], tot[8], run[8];
    #pragma unroll
    for (int ch = 0; ch < 8; ++ch) {
        ebt[ch] = wexcl[w][ch] + incl[ch] - own[ch];
        tot[ch] = wtot[ch];
        run[ch] = 0.f;
    }

    float* CP = ws + CPOFF;
    #pragma unroll
    for (int q = 0; q < 4; ++q) {
        float P[8];
        #pragma unroll
        for (int ch = 0; ch < 8; ++ch) { run[ch] += vals[q][ch]; P[ch] = ebt[ch] + run[ch]; }
        float a = aq[q];
        float lowS = fmaf(0.25f - a, P[0], P[2]);
        float lowC = fmaf(0.25f - a, P[1], P[3]);
        float lower = vals[q][1] * lowS - vals[q][0] * lowC;
        float S4 = tot[4] - P[4], S5 = tot[5] - P[5];
        float S6 = tot[6] - P[6], S7 = tot[7] - P[7];
        float upS = fmaf(0.25f + a, S4, -S6);
        float upC = fmaf(0.25f + a, S5, -S7);
        float upper = vals[q][5] * upS - vals[q][4] * upC;
        CP[vq[q]*4 + d] = (lower + upper) * (1.0f / (float)NC);
    }
}

// ---------- kernel 4: theta_next = gamma + coupling, normalize -------------
__global__ void k_norm(const float* __restrict__ gamma,
                       const float* __restrict__ ws,
                       float* __restrict__ out) {
    int u = blockIdx.x * 256 + threadIdx.x;      // < BATCH*NN
    float4 cp = ((const float4*)(ws + CPOFF))[u];
    float4 g4 = ((const float4*)gamma)[u];
    float tx = g4.x + cp.x, ty = g4.y + cp.y, tz = g4.z + cp.z, tw = g4.w + cp.w;
    float nrm = sqrtf(tx*tx + ty*ty + tz*tz + tw*tw);
    float inv = 1.0f / fmaxf(nrm, 1e-6f);
    ((float4*)out)[u] = make_float4(tx*inv, ty*inv, tz*inv, tw*inv);
}

extern "C" void kernel_launch(void* const* d_in, const int* in_sizes, int n_in,
                              void* d_out, int out_size, void* d_ws, size_t ws_size,
                              hipStream_t stream) {
    const float* theta  = (const float*)d_in[0];
    const float* gamma  = (const float*)d_in[1];
    const float* spikes = (const float*)d_in[2];
    float* out = (float*)d_out;
    float* ws  = (float*)d_ws;

    hipLaunchKernelGGL(k_sort, dim3(NG),           dim3(1024), 0, stream, spikes, ws);
    hipLaunchKernelGGL(k_vals, dim3(NG*NC/256),    dim3(256),  0, stream, theta, ws);
    hipLaunchKernelGGL(k_scan, dim3(NG*4),         dim3(1024), 0, stream, ws);
    hipLaunchKernelGGL(k_norm, dim3(BATCH*NN/256), dim3(256),  0, stream, gamma, ws, out);
}